// Round 10
// baseline (196.153 us; speedup 1.0000x reference)
//
#include <hip/hip_runtime.h>
#include <hip/hip_fp16.h>

#define NN 16384
#define EE 524288
#define DDIM 128
#define HDIM 256
#define CDIM 10
#define GG 64
#define MAXD 128

typedef _Float16 h8 __attribute__((ext_vector_type(8)));
typedef float f4 __attribute__((ext_vector_type(4)));
typedef unsigned short su8 __attribute__((ext_vector_type(8)));

// workspace byte offsets
#define OFF_XH   0ull          // 4 MB fp16 x [NN][128]
#define OFF_ELL  4194304ull    // 4 MB ushort ELL [NN][128] (compact, no flags)
#define OFF_Y1H  16777216ull   // 4 MB fp16 [NN][128]
#define OFF_H1   20971520ull   // 8 MB fp16 [NN][256]
#define OFF_Y2H  29360128ull   // 8 MB fp16 [NN][256]
#define OFF_DEG  37748736ull   // 64 KB int
#define OFF_DIS  37814272ull   // 64 KB float
#define OFF_POOL 37879808ull   // 64 KB (16384 floats)
#define OFF_CNT  37945344ull   // 4 KB (64 floats)
#define OFF_WT1  37949440ull   // 64 KB fp16 Wt1[256][128]
#define OFF_WT2  38014976ull   // 128 KB fp16 Wt2[256][256]
#define OFF_BM   41943040ull   // 32 MB adjacency bitmap [NN][512 words]

// fused init. Edge segment uses fire-and-forget atomicOr into the dense
// bitmap: duplicates are idempotent (dedup disappears), addresses spread
// over 512K cache lines (the R9 postmortem showed deg-array atomicAdd was
// contention-bound at ~1000 RMWs/line). Misc segment also sets the
// diagonal self-loop bit.
__global__ void init_all(const float* __restrict__ x, _Float16* __restrict__ xh,
                         const float* __restrict__ W1, _Float16* __restrict__ wt1,
                         const float* __restrict__ W2, _Float16* __restrict__ wt2,
                         const int* __restrict__ ei, unsigned* __restrict__ bitmap,
                         float* __restrict__ pooled, float* __restrict__ cnt,
                         const int* __restrict__ batch) {
    int b = blockIdx.x, t = threadIdx.x;
    if (b < 2048) {                       // x -> fp16 (float4 per thread)
        int i = (b * 256 + t) * 4;
        float4 v = *(const float4*)(x + i);
        _Float16 o[4] = {(_Float16)v.x, (_Float16)v.y, (_Float16)v.z, (_Float16)v.w};
        *(ushort4*)(xh + i) = *(ushort4*)o;
    } else if (b < 2176) {                // Wt1[n][k] = W1[k][n]
        int i = (b - 2048) * 256 + t;
        int n = i / DDIM, k = i - n * DDIM;
        wt1[i] = (_Float16)W1[k * 256 + n];
    } else if (b < 2432) {                // Wt2[n][k] = W2[k][n]
        int i = (b - 2176) * 256 + t;
        int n = i / HDIM, k = i - n * HDIM;
        wt2[i] = (_Float16)W2[k * 256 + n];
    } else if (b < 2496) {                // per-row misc + cnt + diagonal bit
        int r = (b - 2432) * 256 + t;
        pooled[r] = 0.0f;
        atomicOr(&bitmap[(size_t)r * 512 + (r >> 5)], 1u << (r & 31));
        if (r < GG) {
            int lo = 0, hi = NN;
            while (lo < hi) { int m = (lo + hi) >> 1; if (batch[m] < r) lo = m + 1; else hi = m; }
            int a = lo;
            lo = 0; hi = NN;
            while (lo < hi) { int m = (lo + hi) >> 1; if (batch[m] < r + 1) lo = m + 1; else hi = m; }
            cnt[r] = (float)(lo - a);
        }
    } else {                              // edges: fire-and-forget atomicOr, 2/thread
        int e = ((b - 2496) * 256 + t) * 2;
        int2 s2 = *(const int2*)(ei + e);
        int2 d2 = *(const int2*)(ei + EE + e);
        atomicOr(&bitmap[(size_t)s2.x * 512 + (d2.x >> 5)], 1u << (d2.x & 31));
        atomicOr(&bitmap[(size_t)s2.y * 512 + (d2.y >> 5)], 1u << (d2.y & 31));
    }
}

// bitmap -> compact ELL + deg + dis. One wave per row (4 rows/block).
// Coalesced uint4 reads, wave prefix-scan for slot positions.
__global__ __launch_bounds__(256) void extract_kernel(const unsigned* __restrict__ bitmap,
                                                      unsigned short* __restrict__ ell,
                                                      int* __restrict__ deg,
                                                      float* __restrict__ dis) {
    const int w = threadIdx.x >> 6, lane = threadIdx.x & 63;
    const int row = blockIdx.x * 4 + w;
    const uint4* bmr4 = (const uint4*)(bitmap + (size_t)row * 512);
    uint4 A = bmr4[lane];
    uint4 B = bmr4[lane + 64];
    unsigned wds[8] = {A.x, A.y, A.z, A.w, B.x, B.y, B.z, B.w};
    int cnt = 0;
#pragma unroll
    for (int i = 0; i < 8; i++) cnt += __popc(wds[i]);
    int inc = cnt;
#pragma unroll
    for (int o = 1; o < 64; o <<= 1) {
        int v = __shfl_up(inc, o, 64);
        if (lane >= o) inc += v;
    }
    int p = inc - cnt;                       // exclusive prefix
    const int total = __shfl(inc, 63, 64);
    unsigned short* er = ell + (size_t)row * MAXD;
#pragma unroll
    for (int i = 0; i < 8; i++) {
        unsigned m = wds[i];
        int cbase = (i < 4) ? (lane * 128 + i * 32) : (8192 + lane * 128 + (i - 4) * 32);
        while (m) {
            int bb = __builtin_ctz(m);
            m &= m - 1;
            if (p < MAXD) er[p] = (unsigned short)(cbase + bb);
            p++;
        }
    }
    if (lane == 63) {
        deg[row] = (total > MAXD) ? MAXD : total;
        dis[row] = 1.0f / sqrtf((float)total);
    }
}

// y[row,:] = (fp16)(dis[row] * sum_k dis[col_k] * src[col_k,:])  (proven R3 form;
// ELL is now compact/unique so no flag handling)
template <int COLS>
__global__ __launch_bounds__(256) void spmm_f16(const _Float16* __restrict__ src,
                                                const unsigned short* __restrict__ ell,
                                                const int* __restrict__ deg,
                                                const float* __restrict__ dis,
                                                _Float16* __restrict__ y) {
    constexpr int SEG = COLS / 8;    // lanes per neighbor (16 or 32)
    constexpr int NS  = 64 / SEG;    // neighbor streams per wave (4 or 2)
    __shared__ unsigned scw[4][MAXD];
    const int t    = threadIdx.x;
    const int w    = t >> 6;
    const int lane = t & 63;
    const int row  = blockIdx.x * 4 + w;
    const size_t base = (size_t)row * MAXD;
    {
        int ca = ell[base + lane] & (NN - 1);        // mask keeps stale slots in-bounds
        int cb = ell[base + 64 + lane] & (NN - 1);
        _Float16 ha = (_Float16)dis[ca], hb = (_Float16)dis[cb];
        scw[w][lane]      = (unsigned)ca | ((unsigned)(*(unsigned short*)&ha) << 16);
        scw[w][64 + lane] = (unsigned)cb | ((unsigned)(*(unsigned short*)&hb) << 16);
    }
    __syncthreads();
    const int d = deg[row];
    const float drow = dis[row];
    const int sid = lane / SEG;
    const int l   = lane % SEG;

    float acc[8];
#pragma unroll
    for (int j = 0; j < 8; j++) acc[j] = 0.0f;

#pragma unroll 4
    for (int k = sid; k < d; k += NS) {
        unsigned u = scw[w][k];
        int col = u & 0xFFFF;
        unsigned short wb = (unsigned short)(u >> 16);
        float wgt = (float)(*(_Float16*)&wb);
        su8 hv = *(const su8*)(src + (size_t)col * COLS + l * 8);
#pragma unroll
        for (int j = 0; j < 8; j++) {
            unsigned short hb = hv[j];
            acc[j] = fmaf(wgt, (float)(*(_Float16*)&hb), acc[j]);
        }
    }
#pragma unroll
    for (int off = SEG; off < 64; off <<= 1)
#pragma unroll
        for (int j = 0; j < 8; j++) acc[j] += __shfl_xor(acc[j], off, 64);

    if (lane < SEG) {
        su8 o;
#pragma unroll
        for (int j = 0; j < 8; j++) {
            _Float16 hv = (_Float16)(drow * acc[j]);
            o[j] = *(unsigned short*)&hv;
        }
        *(su8*)(y + (size_t)row * COLS + lane * 8) = o;
    }
}

// ================= MFMA GEMM: 128x64 tile, 256 thr / 4 waves ================
#define ASTR 40   // f16 stride (80 B, 16B-aligned)
#define BSTR 40

#define MFMA_PROLOG                                                            \
    const int r0 = blockIdx.x * 128;                                           \
    const int c0 = blockIdx.y * 64;                                            \
    const int t = threadIdx.x;                                                 \
    const int lane = t & 63, wv = t >> 6;                                      \
    const int wm = wv >> 1, wn = wv & 1;                                       \
    const int qm = lane & 15, qk = lane >> 4;                                  \
    f4 acc[4][2];                                                              \
    _Pragma("unroll") for (int i = 0; i < 4; i++)                              \
        _Pragma("unroll") for (int j = 0; j < 2; j++)                          \
            acc[i][j] = (f4){0.f, 0.f, 0.f, 0.f};

#define MFMA_KLOOP(Aptr, Wtptr, K)                                             \
    for (int k0 = 0; k0 < K; k0 += 32) {                                       \
        __syncthreads();                                                       \
        {                                                                      \
            int r = t >> 1, ko = (t & 1) * 16;                                 \
            const su8* srcA = (const su8*)(Aptr + (size_t)(r0 + r) * K + k0 + ko); \
            su8 a0 = srcA[0], a1 = srcA[1];                                    \
            *(su8*)&As[r * ASTR + ko]     = a0;                                \
            *(su8*)&As[r * ASTR + ko + 8] = a1;                                \
            int n = t >> 2, ko2 = (t & 3) * 8;                                 \
            *(su8*)&Bs[n * BSTR + ko2] =                                       \
                *(const su8*)(Wtptr + (size_t)(c0 + n) * K + k0 + ko2);        \
        }                                                                      \
        __syncthreads();                                                       \
        h8 bfr[2];                                                             \
        _Pragma("unroll") for (int j = 0; j < 2; j++)                          \
            bfr[j] = *(const h8*)&Bs[(wn * 32 + j * 16 + qm) * BSTR + qk * 8]; \
        _Pragma("unroll") for (int i = 0; i < 4; i++) {                        \
            h8 afr = *(const h8*)&As[(wm * 64 + i * 16 + qm) * ASTR + qk * 8]; \
            _Pragma("unroll") for (int j = 0; j < 2; j++)                      \
                acc[i][j] = __builtin_amdgcn_mfma_f32_16x16x32_f16(            \
                    afr, bfr[j], acc[i][j], 0, 0, 0);                          \
        }                                                                      \
    }

// GEMM1: h1 = relu(y1 @ W1 + b1) -> fp16 [NN][256]
template <int K>
__global__ __launch_bounds__(256) void gemm_mfma_f16(
        const _Float16* __restrict__ A, const _Float16* __restrict__ Wt,
        const float* __restrict__ bias, _Float16* __restrict__ H) {
    __shared__ __align__(16) _Float16 As[128 * ASTR];
    __shared__ __align__(16) _Float16 Bs[64 * BSTR];
    __shared__ __align__(16) _Float16 Cs[128 * 72];
    MFMA_PROLOG
    MFMA_KLOOP(A, Wt, K)

    float bv[2];
#pragma unroll
    for (int j = 0; j < 2; j++) bv[j] = bias[c0 + wn * 32 + j * 16 + qm];
#pragma unroll
    for (int i = 0; i < 4; i++)
#pragma unroll
        for (int j = 0; j < 2; j++) {
            int lc = wn * 32 + j * 16 + qm;
#pragma unroll
            for (int rr = 0; rr < 4; rr++) {
                int lr = wm * 64 + i * 16 + qk * 4 + rr;
                Cs[lr * 72 + lc] = (_Float16)fmaxf(acc[i][j][rr] + bv[j], 0.0f);
            }
        }
    __syncthreads();
    {
        int r = t >> 1, half_ = t & 1;
        _Float16* dst = H + (size_t)(r0 + r) * 256 + c0 + half_ * 32;
        const _Float16* srcc = &Cs[r * 72 + half_ * 32];
#pragma unroll
        for (int q = 0; q < 4; q++)
            *(su8*)(dst + q * 8) = *(const su8*)(srcc + q * 8);
    }
}

// GEMM2 + fused mean-pool numerator (no C materialization).
#define NG 8
template <int K>
__global__ __launch_bounds__(256) void gemm_mfma_pool(
        const _Float16* __restrict__ A, const _Float16* __restrict__ Wt,
        const float* __restrict__ bias, const int* __restrict__ batch,
        float* __restrict__ pooled) {
    __shared__ __align__(16) _Float16 As[128 * ASTR];
    __shared__ __align__(16) _Float16 Bs[64 * BSTR];
    __shared__ float pools[NG][68];
    __shared__ int sb[128];
    MFMA_PROLOG
    if (t < 128) sb[t] = batch[r0 + t];
    for (int i = t; i < NG * 68; i += 256) ((float*)pools)[i] = 0.0f;
    MFMA_KLOOP(A, Wt, K)

    float bv[2];
#pragma unroll
    for (int j = 0; j < 2; j++) bv[j] = bias[c0 + wn * 32 + j * 16 + qm];
    __syncthreads();
    const int g0 = sb[0];
#pragma unroll
    for (int i = 0; i < 4; i++)
#pragma unroll
        for (int j = 0; j < 2; j++) {
            int lc = wn * 32 + j * 16 + qm;
#pragma unroll
            for (int rr = 0; rr < 4; rr++) {
                int lr = wm * 64 + i * 16 + qk * 4 + rr;
                int gi = min(sb[lr] - g0, NG - 1);
                float v = fmaxf(acc[i][j][rr] + bv[j], 0.0f);
                atomicAdd(&pools[gi][lc], v);
            }
        }
    __syncthreads();
    const int ng = min(sb[127] - g0 + 1, NG);
    for (int i2 = t; i2 < ng * 64; i2 += 256) {
        int gi = i2 >> 6, c = i2 & 63;
        float v = pools[gi][c];
        if (v != 0.0f) atomicAdd(&pooled[(g0 + gi) * 256 + c0 + c], v);
    }
}

// out[g,c] = (pooled[g,:]/cnt[g]) . Wc[:,c] + bc[c]
__global__ void head_kernel(const float* __restrict__ pooled,
                            const float* __restrict__ cnt,
                            const float* __restrict__ Wc,
                            const float* __restrict__ bc,
                            float* __restrict__ out) {
    int g = blockIdx.x;
    int l = threadIdx.x;  // 64
    float inv = 1.0f / fmaxf(cnt[g], 1.0f);
    float acc[CDIM];
#pragma unroll
    for (int c = 0; c < CDIM; c++) acc[c] = 0.0f;
    for (int t = l; t < 256; t += 64) {
        float pv = pooled[g * 256 + t] * inv;
#pragma unroll
        for (int c = 0; c < CDIM; c++) acc[c] = fmaf(pv, Wc[t * CDIM + c], acc[c]);
    }
#pragma unroll
    for (int c = 0; c < CDIM; c++) {
        float v = acc[c];
        for (int off = 32; off > 0; off >>= 1) v += __shfl_down(v, off, 64);
        if (l == 0) out[g * CDIM + c] = v + bc[c];
    }
}

extern "C" void kernel_launch(void* const* d_in, const int* in_sizes, int n_in,
                              void* d_out, int out_size, void* d_ws, size_t ws_size,
                              hipStream_t stream) {
    const float* x  = (const float*)d_in[0];
    const int*   ei = (const int*)d_in[1];
    const int*   batch = (const int*)d_in[2];
    const float* W1 = (const float*)d_in[3];
    const float* b1 = (const float*)d_in[4];
    const float* W2 = (const float*)d_in[5];
    const float* b2 = (const float*)d_in[6];
    const float* Wc = (const float*)d_in[7];
    const float* bc = (const float*)d_in[8];
    float* out = (float*)d_out;

    char* ws = (char*)d_ws;
    _Float16* xh   = (_Float16*)(ws + OFF_XH);
    unsigned short* ell = (unsigned short*)(ws + OFF_ELL);
    _Float16* y1h  = (_Float16*)(ws + OFF_Y1H);
    _Float16* h1   = (_Float16*)(ws + OFF_H1);
    _Float16* y2h  = (_Float16*)(ws + OFF_Y2H);
    int*   deg     = (int*)(ws + OFF_DEG);
    float* dis     = (float*)(ws + OFF_DIS);
    float* pooled  = (float*)(ws + OFF_POOL);
    float* cnt     = (float*)(ws + OFF_CNT);
    _Float16* wt1  = (_Float16*)(ws + OFF_WT1);
    _Float16* wt2  = (_Float16*)(ws + OFF_WT2);
    unsigned* bitmap = (unsigned*)(ws + OFF_BM);

    // 0) zero the adjacency bitmap (32 MB, ~5.5 us)
    hipMemsetAsync(bitmap, 0, (size_t)NN * 512 * sizeof(unsigned), stream);
    // 1) fused init (x->f16, Wt1, Wt2, misc+diag, edges via fire-and-forget atomicOr)
    init_all<<<3520, 256, 0, stream>>>(x, xh, W1, wt1, W2, wt2, ei, bitmap,
                                       pooled, cnt, batch);
    // 2) bitmap -> compact ELL + deg + dis (replaces dedup)
    extract_kernel<<<NN / 4, 256, 0, stream>>>(bitmap, ell, deg, dis);
    // 3) SpMM1: y1h = Ahat @ xh  [N,128]
    spmm_f16<DDIM><<<NN / 4, 256, 0, stream>>>(xh, ell, deg, dis, y1h);
    // 4) GEMM1 (MFMA): h1 = relu(y1h @ W1 + b1) -> fp16 [NN][256]
    {
        dim3 grid(NN / 128, 256 / 64);
        gemm_mfma_f16<DDIM><<<grid, 256, 0, stream>>>(y1h, wt1, b1, h1);
    }
    // 5) SpMM2: y2h = Ahat @ h1  [N,256]
    spmm_f16<HDIM><<<NN / 4, 256, 0, stream>>>(h1, ell, deg, dis, y2h);
    // 6) GEMM2 (MFMA) + fused pooling numerator
    {
        dim3 grid(NN / 128, 256 / 64);
        gemm_mfma_pool<HDIM><<<grid, 256, 0, stream>>>(y2h, wt2, b2, batch, pooled);
    }
    // 7) head
    head_kernel<<<GG, 64, 0, stream>>>(pooled, cnt, Wc, bc, out);
}

// Round 11
// 195.274 us; speedup vs baseline: 1.0045x; 1.0045x over previous
//
#include <hip/hip_runtime.h>
#include <hip/hip_fp16.h>

#define NN 16384
#define EE 524288
#define DDIM 128
#define HDIM 256
#define CDIM 10
#define GG 64
#define MAXD 128

typedef _Float16 h8 __attribute__((ext_vector_type(8)));
typedef float f4 __attribute__((ext_vector_type(4)));
typedef unsigned short su8 __attribute__((ext_vector_type(8)));

// workspace byte offsets (~38 MB total)
#define OFF_XH   0ull          // 4 MB fp16 x [NN][128]
#define OFF_ELL  4194304ull    // 4 MB ushort ELL [NN][128]
#define OFF_DEG4 8388608ull    // 256 KB int deg4[4][NN] (memset 0 each call)
#define OFF_Y1H  16777216ull   // 4 MB fp16 [NN][128]
#define OFF_H1   20971520ull   // 8 MB fp16 [NN][256]
#define OFF_Y2H  29360128ull   // 8 MB fp16 [NN][256]
#define OFF_DEG  37748736ull   // 64 KB int (compact count, written by dedup)
#define OFF_DIS  37814272ull   // 64 KB float
#define OFF_POOL 37879808ull   // 64 KB (16384 floats)
#define OFF_CNT  37945344ull   // 4 KB (64 floats)
#define OFF_WT1  37949440ull   // 64 KB fp16 Wt1[256][128]
#define OFF_WT2  38014976ull   // 128 KB fp16 Wt2[256][256]

// fused init. EDGE BLOCKS FIRST (0..1023): 2 edges/thread, forward-only.
// 4-WAY SPLIT COUNTERS: edge id mod 4 picks deg4 part p; part p owns ELL
// slots [1+32p, 1+32p+cap_p) (caps 32/32/32/31). R7/R9/R10 established the
// append is line-serialization-bound (~1000 RMWs on each of 1024 lines);
// 4 separate 64KB counter arrays cut RMWs/line 4x. Slot 0 = implicit self.
__global__ void init_all(const float* __restrict__ x, _Float16* __restrict__ xh,
                         const float* __restrict__ W1, _Float16* __restrict__ wt1,
                         const float* __restrict__ W2, _Float16* __restrict__ wt2,
                         const int* __restrict__ ei, unsigned short* __restrict__ ell,
                         int* __restrict__ deg4,
                         float* __restrict__ pooled, float* __restrict__ cnt,
                         const int* __restrict__ batch) {
    int b = blockIdx.x, t = threadIdx.x;
    if (b < 1024) {                       // edge append, 2 edges/thread
        int e = (b * 256 + t) * 2;
        int2 s2 = *(const int2*)(ei + e);
        int2 d2 = *(const int2*)(ei + EE + e);
        int pa = e & 3;                   // e even -> 0 or 2
        int pb = (e + 1) & 3;             // e+1 odd -> 1 or 3
        int capa = (pa == 3) ? 31 : 32;
        int capb = (pb == 3) ? 31 : 32;
        int pos = atomicAdd(&deg4[pa * NN + s2.x], 1);
        if (pos < capa) ell[s2.x * MAXD + 1 + 32 * pa + pos] = (unsigned short)d2.x;
        pos = atomicAdd(&deg4[pb * NN + s2.y], 1);
        if (pos < capb) ell[s2.y * MAXD + 1 + 32 * pb + pos] = (unsigned short)d2.y;
    } else if (b < 3072) {                // x -> fp16 (float4 per thread)
        int i = ((b - 1024) * 256 + t) * 4;
        float4 v = *(const float4*)(x + i);
        _Float16 o[4] = {(_Float16)v.x, (_Float16)v.y, (_Float16)v.z, (_Float16)v.w};
        *(ushort4*)(xh + i) = *(ushort4*)o;
    } else if (b < 3200) {                // Wt1[n][k] = W1[k][n]
        int i = (b - 3072) * 256 + t;
        int n = i / DDIM, k = i - n * DDIM;
        wt1[i] = (_Float16)W1[k * 256 + n];
    } else if (b < 3456) {                // Wt2[n][k] = W2[k][n]
        int i = (b - 3200) * 256 + t;
        int n = i / HDIM, k = i - n * HDIM;
        wt2[i] = (_Float16)W2[k * 256 + n];
    } else {                              // per-row misc + cnt
        int r = (b - 3456) * 256 + t;
        pooled[r] = 0.0f;
        if (r < GG) {
            int lo = 0, hi = NN;
            while (lo < hi) { int m = (lo + hi) >> 1; if (batch[m] < r) lo = m + 1; else hi = m; }
            int a = lo;
            lo = 0; hi = NN;
            while (lo < hi) { int m = (lo + hi) >> 1; if (batch[m] < r + 1) lo = m + 1; else hi = m; }
            cnt[r] = (float)(lo - a);
        }
    }
}

// O(d) bitmap dedup + COMPACTION. One wave per row, 2 KB LDS bitmap.
// Validity of slot j from the 4 part-counters; uniqueness via LDS
// test-and-set; valid&unique entries ballot-compacted to slots [0, nd).
// deg <- nd (unique count), dis <- 1/sqrt(nd). spmm needs no flag logic.
__global__ __launch_bounds__(256) void dedup_kernel(unsigned short* __restrict__ ell,
                                                    const int* __restrict__ deg4,
                                                    int* __restrict__ deg,
                                                    float* __restrict__ dis) {
    __shared__ unsigned bm[4][NN / 32];   // 4 rows x 2 KB
    const int w = threadIdx.x >> 6, lane = threadIdx.x & 63;
    const int row = blockIdx.x * 4 + w;
    for (int i = lane; i < NN / 32; i += 64) bm[w][i] = 0u;
    __syncthreads();
    const int cp0 = min(deg4[row], 32);
    const int cp1 = min(deg4[NN + row], 32);
    const int cp2 = min(deg4[2 * NN + row], 32);
    const int cp3 = min(deg4[3 * NN + row], 31);
    const size_t base = (size_t)row * MAXD;
    const int c0 = (lane == 0) ? row : (ell[base + lane] & (NN - 1));
    const int c1 = ell[base + 64 + lane] & (NN - 1);
    bool v0, v1;
    if (lane == 0) v0 = true;
    else {
        int p = (lane - 1) >> 5, o = (lane - 1) & 31;
        int c = (p == 0) ? cp0 : cp1;     // slots 1..63 -> parts 0,1
        v0 = o < c;
    }
    {
        int j = 63 + lane;                // slot 64+lane -> (j)>>5 with j=slot-1
        int p = j >> 5, o = j & 31;       // parts 1,2,3
        int c = (p == 1) ? cp1 : (p == 2) ? cp2 : cp3;
        v1 = o < c;
    }
    bool k0 = false, k1 = false;
    if (v0) k0 = ((atomicOr(&bm[w][c0 >> 5], 1u << (c0 & 31)) >> (c0 & 31)) & 1u) == 0u;
    if (v1) k1 = ((atomicOr(&bm[w][c1 >> 5], 1u << (c1 & 31)) >> (c1 & 31)) & 1u) == 0u;
    unsigned long long m0 = __ballot(k0);
    unsigned long long m1 = __ballot(k1);
    const int nd = __popcll(m0) + __popcll(m1);
    unsigned long long below = (lane == 0) ? 0ull : ((~0ull) >> (64 - lane));
    int p0 = __popcll(m0 & below);
    int p1 = __popcll(m0) + __popcll(m1 & below);
    if (k0) ell[base + p0] = (unsigned short)c0;
    if (k1) ell[base + p1] = (unsigned short)c1;
    if (lane == 0) {
        deg[row] = nd;
        dis[row] = 1.0f / sqrtf((float)nd);
    }
}

// y[row,:] = (fp16)(dis[row] * sum_k dis[col_k] * src[col_k,:])
// ELL is compact+unique after dedup: no flags, d = nd.  (proven R3 form)
template <int COLS>
__global__ __launch_bounds__(256) void spmm_f16(const _Float16* __restrict__ src,
                                                const unsigned short* __restrict__ ell,
                                                const int* __restrict__ deg,
                                                const float* __restrict__ dis,
                                                _Float16* __restrict__ y) {
    constexpr int SEG = COLS / 8;    // lanes per neighbor (16 or 32)
    constexpr int NS  = 64 / SEG;    // neighbor streams per wave (4 or 2)
    __shared__ unsigned scw[4][MAXD];
    const int t    = threadIdx.x;
    const int w    = t >> 6;
    const int lane = t & 63;
    const int row  = blockIdx.x * 4 + w;
    const size_t base = (size_t)row * MAXD;
    {
        int ca = ell[base + lane] & (NN - 1);        // mask: stale slots stay in-bounds
        int cb = ell[base + 64 + lane] & (NN - 1);
        _Float16 ha = (_Float16)dis[ca], hb = (_Float16)dis[cb];
        scw[w][lane]      = (unsigned)ca | ((unsigned)(*(unsigned short*)&ha) << 16);
        scw[w][64 + lane] = (unsigned)cb | ((unsigned)(*(unsigned short*)&hb) << 16);
    }
    __syncthreads();
    const int d = deg[row];
    const float drow = dis[row];
    const int sid = lane / SEG;
    const int l   = lane % SEG;

    float acc[8];
#pragma unroll
    for (int j = 0; j < 8; j++) acc[j] = 0.0f;

#pragma unroll 4
    for (int k = sid; k < d; k += NS) {
        unsigned u = scw[w][k];
        int col = u & 0xFFFF;
        unsigned short wb = (unsigned short)(u >> 16);
        float wgt = (float)(*(_Float16*)&wb);
        su8 hv = *(const su8*)(src + (size_t)col * COLS + l * 8);
#pragma unroll
        for (int j = 0; j < 8; j++) {
            unsigned short hb = hv[j];
            acc[j] = fmaf(wgt, (float)(*(_Float16*)&hb), acc[j]);
        }
    }
#pragma unroll
    for (int off = SEG; off < 64; off <<= 1)
#pragma unroll
        for (int j = 0; j < 8; j++) acc[j] += __shfl_xor(acc[j], off, 64);

    if (lane < SEG) {
        su8 o;
#pragma unroll
        for (int j = 0; j < 8; j++) {
            _Float16 hv = (_Float16)(drow * acc[j]);
            o[j] = *(unsigned short*)&hv;
        }
        *(su8*)(y + (size_t)row * COLS + lane * 8) = o;
    }
}

// ================= MFMA GEMM: 128x64 tile, 256 thr / 4 waves ================
#define ASTR 40   // f16 stride (80 B, 16B-aligned)
#define BSTR 40

#define MFMA_PROLOG                                                            \
    const int r0 = blockIdx.x * 128;                                           \
    const int c0 = blockIdx.y * 64;                                            \
    const int t = threadIdx.x;                                                 \
    const int lane = t & 63, wv = t >> 6;                                      \
    const int wm = wv >> 1, wn = wv & 1;                                       \
    const int qm = lane & 15, qk = lane >> 4;                                  \
    f4 acc[4][2];                                                              \
    _Pragma("unroll") for (int i = 0; i < 4; i++)                              \
        _Pragma("unroll") for (int j = 0; j < 2; j++)                          \
            acc[i][j] = (f4){0.f, 0.f, 0.f, 0.f};

#define MFMA_KLOOP(Aptr, Wtptr, K)                                             \
    for (int k0 = 0; k0 < K; k0 += 32) {                                       \
        __syncthreads();                                                       \
        {                                                                      \
            int r = t >> 1, ko = (t & 1) * 16;                                 \
            const su8* srcA = (const su8*)(Aptr + (size_t)(r0 + r) * K + k0 + ko); \
            su8 a0 = srcA[0], a1 = srcA[1];                                    \
            *(su8*)&As[r * ASTR + ko]     = a0;                                \
            *(su8*)&As[r * ASTR + ko + 8] = a1;                                \
            int n = t >> 2, ko2 = (t & 3) * 8;                                 \
            *(su8*)&Bs[n * BSTR + ko2] =                                       \
                *(const su8*)(Wtptr + (size_t)(c0 + n) * K + k0 + ko2);        \
        }                                                                      \
        __syncthreads();                                                       \
        h8 bfr[2];                                                             \
        _Pragma("unroll") for (int j = 0; j < 2; j++)                          \
            bfr[j] = *(const h8*)&Bs[(wn * 32 + j * 16 + qm) * BSTR + qk * 8]; \
        _Pragma("unroll") for (int i = 0; i < 4; i++) {                        \
            h8 afr = *(const h8*)&As[(wm * 64 + i * 16 + qm) * ASTR + qk * 8]; \
            _Pragma("unroll") for (int j = 0; j < 2; j++)                      \
                acc[i][j] = __builtin_amdgcn_mfma_f32_16x16x32_f16(            \
                    afr, bfr[j], acc[i][j], 0, 0, 0);                          \
        }                                                                      \
    }

// GEMM1: h1 = relu(y1 @ W1 + b1) -> fp16 [NN][256]
template <int K>
__global__ __launch_bounds__(256) void gemm_mfma_f16(
        const _Float16* __restrict__ A, const _Float16* __restrict__ Wt,
        const float* __restrict__ bias, _Float16* __restrict__ H) {
    __shared__ __align__(16) _Float16 As[128 * ASTR];
    __shared__ __align__(16) _Float16 Bs[64 * BSTR];
    __shared__ __align__(16) _Float16 Cs[128 * 72];
    MFMA_PROLOG
    MFMA_KLOOP(A, Wt, K)

    float bv[2];
#pragma unroll
    for (int j = 0; j < 2; j++) bv[j] = bias[c0 + wn * 32 + j * 16 + qm];
#pragma unroll
    for (int i = 0; i < 4; i++)
#pragma unroll
        for (int j = 0; j < 2; j++) {
            int lc = wn * 32 + j * 16 + qm;
#pragma unroll
            for (int rr = 0; rr < 4; rr++) {
                int lr = wm * 64 + i * 16 + qk * 4 + rr;
                Cs[lr * 72 + lc] = (_Float16)fmaxf(acc[i][j][rr] + bv[j], 0.0f);
            }
        }
    __syncthreads();
    {
        int r = t >> 1, half_ = t & 1;
        _Float16* dst = H + (size_t)(r0 + r) * 256 + c0 + half_ * 32;
        const _Float16* srcc = &Cs[r * 72 + half_ * 32];
#pragma unroll
        for (int q = 0; q < 4; q++)
            *(su8*)(dst + q * 8) = *(const su8*)(srcc + q * 8);
    }
}

// GEMM2 + fused mean-pool numerator (no C materialization).
#define NG 8
template <int K>
__global__ __launch_bounds__(256) void gemm_mfma_pool(
        const _Float16* __restrict__ A, const _Float16* __restrict__ Wt,
        const float* __restrict__ bias, const int* __restrict__ batch,
        float* __restrict__ pooled) {
    __shared__ __align__(16) _Float16 As[128 * ASTR];
    __shared__ __align__(16) _Float16 Bs[64 * BSTR];
    __shared__ float pools[NG][68];
    __shared__ int sb[128];
    MFMA_PROLOG
    if (t < 128) sb[t] = batch[r0 + t];
    for (int i = t; i < NG * 68; i += 256) ((float*)pools)[i] = 0.0f;
    MFMA_KLOOP(A, Wt, K)

    float bv[2];
#pragma unroll
    for (int j = 0; j < 2; j++) bv[j] = bias[c0 + wn * 32 + j * 16 + qm];
    __syncthreads();
    const int g0 = sb[0];
#pragma unroll
    for (int i = 0; i < 4; i++)
#pragma unroll
        for (int j = 0; j < 2; j++) {
            int lc = wn * 32 + j * 16 + qm;
#pragma unroll
            for (int rr = 0; rr < 4; rr++) {
                int lr = wm * 64 + i * 16 + qk * 4 + rr;
                int gi = min(sb[lr] - g0, NG - 1);
                float v = fmaxf(acc[i][j][rr] + bv[j], 0.0f);
                atomicAdd(&pools[gi][lc], v);
            }
        }
    __syncthreads();
    const int ng = min(sb[127] - g0 + 1, NG);
    for (int i2 = t; i2 < ng * 64; i2 += 256) {
        int gi = i2 >> 6, c = i2 & 63;
        float v = pools[gi][c];
        if (v != 0.0f) atomicAdd(&pooled[(g0 + gi) * 256 + c0 + c], v);
    }
}

// out[g,c] = (pooled[g,:]/cnt[g]) . Wc[:,c] + bc[c]
__global__ void head_kernel(const float* __restrict__ pooled,
                            const float* __restrict__ cnt,
                            const float* __restrict__ Wc,
                            const float* __restrict__ bc,
                            float* __restrict__ out) {
    int g = blockIdx.x;
    int l = threadIdx.x;  // 64
    float inv = 1.0f / fmaxf(cnt[g], 1.0f);
    float acc[CDIM];
#pragma unroll
    for (int c = 0; c < CDIM; c++) acc[c] = 0.0f;
    for (int t = l; t < 256; t += 64) {
        float pv = pooled[g * 256 + t] * inv;
#pragma unroll
        for (int c = 0; c < CDIM; c++) acc[c] = fmaf(pv, Wc[t * CDIM + c], acc[c]);
    }
#pragma unroll
    for (int c = 0; c < CDIM; c++) {
        float v = acc[c];
        for (int off = 32; off > 0; off >>= 1) v += __shfl_down(v, off, 64);
        if (l == 0) out[g * CDIM + c] = v + bc[c];
    }
}

extern "C" void kernel_launch(void* const* d_in, const int* in_sizes, int n_in,
                              void* d_out, int out_size, void* d_ws, size_t ws_size,
                              hipStream_t stream) {
    const float* x  = (const float*)d_in[0];
    const int*   ei = (const int*)d_in[1];
    const int*   batch = (const int*)d_in[2];
    const float* W1 = (const float*)d_in[3];
    const float* b1 = (const float*)d_in[4];
    const float* W2 = (const float*)d_in[5];
    const float* b2 = (const float*)d_in[6];
    const float* Wc = (const float*)d_in[7];
    const float* bc = (const float*)d_in[8];
    float* out = (float*)d_out;

    char* ws = (char*)d_ws;
    _Float16* xh   = (_Float16*)(ws + OFF_XH);
    unsigned short* ell = (unsigned short*)(ws + OFF_ELL);
    int*   deg4    = (int*)(ws + OFF_DEG4);
    _Float16* y1h  = (_Float16*)(ws + OFF_Y1H);
    _Float16* h1   = (_Float16*)(ws + OFF_H1);
    _Float16* y2h  = (_Float16*)(ws + OFF_Y2H);
    int*   deg     = (int*)(ws + OFF_DEG);
    float* dis     = (float*)(ws + OFF_DIS);
    float* pooled  = (float*)(ws + OFF_POOL);
    float* cnt     = (float*)(ws + OFF_CNT);
    _Float16* wt1  = (_Float16*)(ws + OFF_WT1);
    _Float16* wt2  = (_Float16*)(ws + OFF_WT2);

    // 0) deg4 = 0 (256 KB)
    hipMemsetAsync(deg4, 0, 4 * NN * sizeof(int), stream);
    // 1) fused init (edge blocks first; 4-way split counters)
    init_all<<<3520, 256, 0, stream>>>(x, xh, W1, wt1, W2, wt2, ei, ell, deg4,
                                       pooled, cnt, batch);
    // 2) dedup + compaction -> compact ELL, deg, dis
    dedup_kernel<<<NN / 4, 256, 0, stream>>>(ell, deg4, deg, dis);
    // 3) SpMM1: y1h = Ahat @ xh  [N,128]
    spmm_f16<DDIM><<<NN / 4, 256, 0, stream>>>(xh, ell, deg, dis, y1h);
    // 4) GEMM1 (MFMA): h1 = relu(y1h @ W1 + b1) -> fp16 [NN][256]
    {
        dim3 grid(NN / 128, 256 / 64);
        gemm_mfma_f16<DDIM><<<grid, 256, 0, stream>>>(y1h, wt1, b1, h1);
    }
    // 5) SpMM2: y2h = Ahat @ h1  [N,256]
    spmm_f16<HDIM><<<NN / 4, 256, 0, stream>>>(h1, ell, deg, dis, y2h);
    // 6) GEMM2 (MFMA) + fused pooling numerator
    {
        dim3 grid(NN / 128, 256 / 64);
        gemm_mfma_pool<HDIM><<<grid, 256, 0, stream>>>(y2h, wt2, b2, batch, pooled);
    }
    // 7) head
    head_kernel<<<GG, 64, 0, stream>>>(pooled, cnt, Wc, bc, out);
}